// Round 2
// baseline (1283.066 us; speedup 1.0000x reference)
//
#include <hip/hip_runtime.h>

#define N_NODES 50000
#define N_EDGES 800000
#define N_META 3
#define IN_DIM 256
#define HD 128
#define HEADS 8
#define HID 16
#define OUT_DIM 8

// ---------------- GEMM: feat = h @ fc_w[m]  (f32 x f32 -> f32) ----------------
__global__ __launch_bounds__(256)
void gemm_feat_kernel(const float* __restrict__ A,   // [N,256]
                      const float* __restrict__ B,   // [256,128]
                      float* __restrict__ C,         // [N,128]
                      int nrows) {
  __shared__ float As[16][68];
  __shared__ float Bs[16][64];
  int tid = threadIdx.x;
  int tx = tid & 15, ty = tid >> 4;
  int row0 = blockIdx.x * 64;
  int col0 = blockIdx.y * 64;
  float acc[4][4] = {};
  for (int k0 = 0; k0 < IN_DIM; k0 += 16) {
    int r = tid >> 2;
    int kk = (tid & 3) * 4;
    int gr = row0 + r;
    float4 a = (gr < nrows) ? *(const float4*)(A + (size_t)gr * IN_DIM + k0 + kk)
                            : make_float4(0.f, 0.f, 0.f, 0.f);
    As[kk+0][r] = a.x; As[kk+1][r] = a.y; As[kk+2][r] = a.z; As[kk+3][r] = a.w;
    int br = tid >> 4;
    int bc = (tid & 15) * 4;
    float4 b = *(const float4*)(B + (size_t)(k0 + br) * HD + col0 + bc);
    Bs[br][bc+0] = b.x; Bs[br][bc+1] = b.y; Bs[br][bc+2] = b.z; Bs[br][bc+3] = b.w;
    __syncthreads();
    #pragma unroll
    for (int k = 0; k < 16; ++k) {
      float a0 = As[k][ty*4+0], a1 = As[k][ty*4+1], a2 = As[k][ty*4+2], a3 = As[k][ty*4+3];
      float b0 = Bs[k][tx*4+0], b1 = Bs[k][tx*4+1], b2 = Bs[k][tx*4+2], b3 = Bs[k][tx*4+3];
      acc[0][0]+=a0*b0; acc[0][1]+=a0*b1; acc[0][2]+=a0*b2; acc[0][3]+=a0*b3;
      acc[1][0]+=a1*b0; acc[1][1]+=a1*b1; acc[1][2]+=a1*b2; acc[1][3]+=a1*b3;
      acc[2][0]+=a2*b0; acc[2][1]+=a2*b1; acc[2][2]+=a2*b2; acc[2][3]+=a2*b3;
      acc[3][0]+=a3*b0; acc[3][1]+=a3*b1; acc[3][2]+=a3*b2; acc[3][3]+=a3*b3;
    }
    __syncthreads();
  }
  #pragma unroll
  for (int i = 0; i < 4; ++i) {
    int gr = row0 + ty*4 + i;
    if (gr < nrows) {
      float4 o = make_float4(acc[i][0], acc[i][1], acc[i][2], acc[i][3]);
      *(float4*)(C + (size_t)gr * HD + col0 + tx*4) = o;
    }
  }
}

// ---------------- el/er per (node, head) --------------------------------------
__global__ __launch_bounds__(256)
void el_er_kernel(const float* __restrict__ feat,
                  const float* __restrict__ al,
                  const float* __restrict__ ar,
                  float* __restrict__ el, float* __restrict__ er) {
  int i = blockIdx.x * blockDim.x + threadIdx.x;
  if (i >= N_NODES * HEADS) return;
  int node = i >> 3, hh = i & 7;
  const float* f = feat + (size_t)node * HD + hh * HID;
  float sl = 0.f, sr = 0.f;
  #pragma unroll
  for (int d = 0; d < HID; ++d) {
    float v = f[d];
    sl += v * al[hh*HID + d];
    sr += v * ar[hh*HID + d];
  }
  el[i] = sl; er[i] = sr;
}

// ---------------- CSR build ---------------------------------------------------
__global__ __launch_bounds__(256)
void hist_kernel(const int* __restrict__ dst, int* __restrict__ cnt) {
  int e = blockIdx.x * blockDim.x + threadIdx.x;
  if (e < N_EDGES) atomicAdd(&cnt[dst[e]], 1);
}

__global__ __launch_bounds__(1024)
void exscan_kernel(const int* __restrict__ in, int* __restrict__ out, int n) {
  __shared__ int wsum[16];
  __shared__ int carry;
  int tid = threadIdx.x, lane = tid & 63, wid = tid >> 6;
  if (tid == 0) carry = 0;
  __syncthreads();
  for (int base = 0; base < n; base += 1024) {
    int i = base + tid;
    int v = (i < n) ? in[i] : 0;
    int s = v;
    #pragma unroll
    for (int d = 1; d < 64; d <<= 1) {
      int t = __shfl_up(s, d);
      if (lane >= d) s += t;
    }
    if (lane == 63) wsum[wid] = s;
    __syncthreads();
    if (wid == 0 && lane < 16) {
      int ws = wsum[lane];
      #pragma unroll
      for (int d = 1; d < 16; d <<= 1) {
        int t = __shfl_up(ws, d);
        if (lane >= d) ws += t;
      }
      wsum[lane] = ws;
    }
    __syncthreads();
    int woff = (wid == 0) ? 0 : wsum[wid - 1];
    int incl = s + woff;
    if (i < n) out[i] = carry + incl - v;
    int total = wsum[15];
    __syncthreads();
    if (tid == 0) carry += total;
    __syncthreads();
  }
  if (tid == 0) out[n] = carry;
}

__global__ __launch_bounds__(256)
void scatter_kernel(const int* __restrict__ src, const int* __restrict__ dst,
                    const int* __restrict__ offs, int* __restrict__ fill,
                    int* __restrict__ csr) {
  int e = blockIdx.x * blockDim.x + threadIdx.x;
  if (e >= N_EDGES) return;
  int d = dst[e];
  int pos = offs[d] + atomicAdd(&fill[d], 1);
  csr[pos] = src[e];
}

// ---------------- GAT aggregation: one wave per dst node ----------------------
__global__ __launch_bounds__(256)
void aggregate_kernel(const int* __restrict__ offs, const int* __restrict__ csr,
                      const float* __restrict__ feat,
                      const float* __restrict__ el, const float* __restrict__ er,
                      float* __restrict__ z) {
  int wave = blockIdx.x * 4 + (threadIdx.x >> 6);
  if (wave >= N_NODES) return;
  int lane = threadIdx.x & 63;
  int dst = wave;
  int beg = offs[dst], end = offs[dst + 1];
  int hh = lane >> 3;
  int sub = lane & 7;
  float erh = er[dst * HEADS + hh];
  float mx = -1e30f;
  for (int i = beg + sub; i < end; i += 8) {
    int s = csr[i];
    float e = el[s * HEADS + hh] + erh;
    e = e > 0.f ? e : 0.2f * e;
    mx = fmaxf(mx, e);
  }
  mx = fmaxf(mx, __shfl_xor(mx, 1));
  mx = fmaxf(mx, __shfl_xor(mx, 2));
  mx = fmaxf(mx, __shfl_xor(mx, 4));
  float ssum = 0.f, a0 = 0.f, a1 = 0.f;
  for (int i = beg; i < end; ++i) {
    int s = csr[i];
    float e = el[s * HEADS + hh] + erh;
    e = e > 0.f ? e : 0.2f * e;
    float ex = __expf(e - mx);
    ssum += ex;
    float2 v = *(const float2*)(feat + (size_t)s * HD + lane * 2);
    a0 += ex * v.x;
    a1 += ex * v.y;
  }
  float inv = (end > beg) ? 1.f / ssum : 0.f;
  a0 *= inv; a1 *= inv;
  a0 = a0 > 0.f ? a0 : expm1f(a0);
  a1 = a1 > 0.f ? a1 : expm1f(a1);
  z[(size_t)dst * HD + lane * 2]     = a0;
  z[(size_t)dst * HD + lane * 2 + 1] = a1;
}

// ---------------- w[n] = tanh(z @ sa_w1 + b1) @ sa_w2 -------------------------
__global__ __launch_bounds__(256)
void w_gemm_kernel(const float* __restrict__ Z,     // [N,128]
                   const float* __restrict__ W1,    // [128,128]
                   const float* __restrict__ B1,    // [128]
                   const float* __restrict__ W2,    // [128]
                   float* __restrict__ wout, int nrows) {
  __shared__ float As[16][68];
  __shared__ float Bs[16][64];
  int tid = threadIdx.x;
  int tx = tid & 15, ty = tid >> 4;
  int row0 = blockIdx.x * 64;
  int col0 = blockIdx.y * 64;
  float acc[4][4] = {};
  for (int k0 = 0; k0 < HD; k0 += 16) {
    int r = tid >> 2;
    int kk = (tid & 3) * 4;
    int gr = row0 + r;
    float4 a = (gr < nrows) ? *(const float4*)(Z + (size_t)gr * HD + k0 + kk)
                            : make_float4(0.f, 0.f, 0.f, 0.f);
    As[kk+0][r] = a.x; As[kk+1][r] = a.y; As[kk+2][r] = a.z; As[kk+3][r] = a.w;
    int br = tid >> 4;
    int bc = (tid & 15) * 4;
    float4 b = *(const float4*)(W1 + (size_t)(k0 + br) * HD + col0 + bc);
    Bs[br][bc+0] = b.x; Bs[br][bc+1] = b.y; Bs[br][bc+2] = b.z; Bs[br][bc+3] = b.w;
    __syncthreads();
    #pragma unroll
    for (int k = 0; k < 16; ++k) {
      float a0 = As[k][ty*4+0], a1 = As[k][ty*4+1], a2 = As[k][ty*4+2], a3 = As[k][ty*4+3];
      float b0 = Bs[k][tx*4+0], b1 = Bs[k][tx*4+1], b2 = Bs[k][tx*4+2], b3 = Bs[k][tx*4+3];
      acc[0][0]+=a0*b0; acc[0][1]+=a0*b1; acc[0][2]+=a0*b2; acc[0][3]+=a0*b3;
      acc[1][0]+=a1*b0; acc[1][1]+=a1*b1; acc[1][2]+=a1*b2; acc[1][3]+=a1*b3;
      acc[2][0]+=a2*b0; acc[2][1]+=a2*b1; acc[2][2]+=a2*b2; acc[2][3]+=a2*b3;
      acc[3][0]+=a3*b0; acc[3][1]+=a3*b1; acc[3][2]+=a3*b2; acc[3][3]+=a3*b3;
    }
    __syncthreads();
  }
  float b1c[4], w2c[4];
  #pragma unroll
  for (int j = 0; j < 4; ++j) {
    int col = col0 + tx * 4 + j;
    b1c[j] = B1[col];
    w2c[j] = W2[col];
  }
  #pragma unroll
  for (int i = 0; i < 4; ++i) {
    float p = 0.f;
    #pragma unroll
    for (int j = 0; j < 4; ++j) p += tanhf(acc[i][j] + b1c[j]) * w2c[j];
    #pragma unroll
    for (int d = 1; d < 16; d <<= 1) p += __shfl_xor(p, d);
    int gr = row0 + ty * 4 + i;
    if (tx == 0 && gr < nrows) atomicAdd(&wout[gr], p);
  }
}

// ---------------- softmax over nodes + fused accumulation ---------------------
__global__ __launch_bounds__(256)
void wmax_part_kernel(const float* __restrict__ w, float* __restrict__ pm, int n) {
  __shared__ float red[4];
  int tid = threadIdx.x;
  float mx = -1e30f;
  for (int i = blockIdx.x * 256 + tid; i < n; i += 64 * 256) mx = fmaxf(mx, w[i]);
  #pragma unroll
  for (int d = 32; d; d >>= 1) mx = fmaxf(mx, __shfl_xor(mx, d));
  if ((tid & 63) == 0) red[tid >> 6] = mx;
  __syncthreads();
  if (tid == 0) pm[blockIdx.x] = fmaxf(fmaxf(red[0], red[1]), fmaxf(red[2], red[3]));
}

__global__ void wmax_final_kernel(const float* __restrict__ pm, float* __restrict__ wmax) {
  float mx = pm[threadIdx.x];
  #pragma unroll
  for (int d = 32; d; d >>= 1) mx = fmaxf(mx, __shfl_xor(mx, d));
  if (threadIdx.x == 0) *wmax = mx;
}

__global__ __launch_bounds__(128)
void fused_acc_kernel(const float* __restrict__ z, const float* __restrict__ w,
                      const float* __restrict__ wmax, float* __restrict__ num,
                      float* __restrict__ den, int n) {
  int t = threadIdx.x;
  float wm = *wmax;
  float ln = 0.f, ld = 0.f;
  for (int node = blockIdx.x; node < n; node += gridDim.x) {
    float e = __expf(w[node] - wm);
    ln += e * z[(size_t)node * HD + t];
    ld += e;
  }
  atomicAdd(&num[t], ln);
  if (t == 0) atomicAdd(den, ld);
}

// ---------------- final: out = (num/den) @ pred_w + pred_b --------------------
__global__ void final_kernel(const float* __restrict__ num, const float* __restrict__ den,
                             const float* __restrict__ PW,
                             const float* __restrict__ PB,
                             float* __restrict__ out) {
  int t = threadIdx.x;
  if (t >= N_META * OUT_DIM) return;
  int m = t >> 3, o = t & 7;
  float inv = 1.0f / den[m];
  float s = 0.f;
  for (int k = 0; k < HD; ++k) s += num[m * HD + k] * PW[k * OUT_DIM + o];
  out[t] = s * inv + PB[o];
}

extern "C" void kernel_launch(void* const* d_in, const int* in_sizes, int n_in,
                              void* d_out, int out_size, void* d_ws, size_t ws_size,
                              hipStream_t stream) {
  (void)in_sizes; (void)n_in; (void)out_size; (void)ws_size;
  const float* h     = (const float*)d_in[0];
  const int*   edges = (const int*)d_in[1];
  const float* fcw   = (const float*)d_in[2];
  const float* al    = (const float*)d_in[3];
  const float* ar    = (const float*)d_in[4];
  const float* w1    = (const float*)d_in[5];
  const float* b1    = (const float*)d_in[6];
  const float* w2    = (const float*)d_in[7];
  const float* pw    = (const float*)d_in[8];
  const float* pb    = (const float*)d_in[9];
  float* out = (float*)d_out;

  char* ws = (char*)d_ws;
  size_t off = 0;
  auto alloc = [&](size_t bytes) -> void* {
    void* p = ws + off;
    off = (off + bytes + 255) & ~(size_t)255;
    return p;
  };
  float* feat = (float*)alloc((size_t)N_NODES * HD * 4);
  float* z    = (float*)alloc((size_t)N_NODES * HD * 4);
  float* el   = (float*)alloc((size_t)N_NODES * HEADS * 4);
  float* er   = (float*)alloc((size_t)N_NODES * HEADS * 4);
  int*   cntfill = (int*)alloc((size_t)2 * N_NODES * 4);
  int*   cnt  = cntfill;
  int*   fill = cntfill + N_NODES;
  int*   offs = (int*)alloc((size_t)(N_NODES + 1) * 4);
  int*   csr  = (int*)alloc((size_t)N_EDGES * 4);
  float* wnode = (float*)alloc((size_t)N_NODES * 4);
  float* pm    = (float*)alloc(64 * 4);
  float* wmax  = (float*)alloc(N_META * 4);
  float* numden = (float*)alloc((N_META * HD + N_META) * 4);
  float* num = numden;
  float* den = numden + N_META * HD;

  hipMemsetAsync(numden, 0, (N_META * HD + N_META) * 4, stream);

  dim3 gemm_grid((N_NODES + 63) / 64, 2);
  for (int m = 0; m < N_META; ++m) {
    const float* Bm = fcw + (size_t)m * IN_DIM * HD;
    const int* src = edges + (size_t)m * 2 * N_EDGES;
    const int* dst = src + N_EDGES;

    gemm_feat_kernel<<<gemm_grid, 256, 0, stream>>>(h, Bm, feat, N_NODES);
    el_er_kernel<<<(N_NODES * HEADS + 255) / 256, 256, 0, stream>>>(
        feat, al + m * HEADS * HID, ar + m * HEADS * HID, el, er);
    hipMemsetAsync(cntfill, 0, (size_t)2 * N_NODES * 4, stream);
    hist_kernel<<<(N_EDGES + 255) / 256, 256, 0, stream>>>(dst, cnt);
    exscan_kernel<<<1, 1024, 0, stream>>>(cnt, offs, N_NODES);
    scatter_kernel<<<(N_EDGES + 255) / 256, 256, 0, stream>>>(src, dst, offs, fill, csr);
    aggregate_kernel<<<(N_NODES + 3) / 4, 256, 0, stream>>>(offs, csr, feat, el, er, z);
    hipMemsetAsync(wnode, 0, (size_t)N_NODES * 4, stream);
    w_gemm_kernel<<<gemm_grid, 256, 0, stream>>>(z, w1, b1, w2, wnode, N_NODES);
    wmax_part_kernel<<<64, 256, 0, stream>>>(wnode, pm, N_NODES);
    wmax_final_kernel<<<1, 64, 0, stream>>>(pm, wmax + m);
    fused_acc_kernel<<<256, 128, 0, stream>>>(z, wnode, wmax + m, num + m * HD, den + m, N_NODES);
  }
  final_kernel<<<1, 64, 0, stream>>>(num, den, pw, pb, out);
}

// Round 3
// 798.787 us; speedup vs baseline: 1.6063x; 1.6063x over previous
//
#include <hip/hip_runtime.h>

#define N_NODES 50000
#define N_EDGES 800000
#define N_META 3
#define IN_DIM 256
#define HD 128
#define HEADS 8
#define HID 16
#define OUT_DIM 8

using bf16x8 = __attribute__((ext_vector_type(8))) short;
using f32x4  = __attribute__((ext_vector_type(4))) float;

__device__ __forceinline__ float bf2f(unsigned short u) {
  union { unsigned int i; float f; } x; x.i = ((unsigned int)u) << 16; return x.f;
}
__device__ __forceinline__ unsigned short f2bf(float f) {
  union { float f; unsigned int i; } x; x.f = f;
  unsigned int r = x.i + 0x7fffu + ((x.i >> 16) & 1u);
  return (unsigned short)(r >> 16);
}
__device__ __forceinline__ unsigned int encf(float f) {
  unsigned int u = __float_as_uint(f);
  return (u & 0x80000000u) ? ~u : (u | 0x80000000u);
}
__device__ __forceinline__ float decf(unsigned int u) {
  return (u & 0x80000000u) ? __uint_as_float(u & 0x7fffffffu) : __uint_as_float(~u);
}

// ---------------- prep: fcw -> fcwT bf16 [M][128][256]; w1 -> w1T bf16 [128][128]
__global__ __launch_bounds__(256)
void prep_kernel(const float* __restrict__ fcw, const float* __restrict__ w1,
                 unsigned short* __restrict__ fcwT, unsigned short* __restrict__ w1T) {
  int i = blockIdx.x * 256 + threadIdx.x;
  const int NFC = N_META * IN_DIM * HD;
  if (i < NFC) {
    int p = i / (IN_DIM * HD);
    int rem = i - p * (IN_DIM * HD);
    int k = rem / HD, n = rem - k * HD;
    fcwT[(size_t)p * HD * IN_DIM + n * IN_DIM + k] = f2bf(fcw[i]);
  } else if (i < NFC + HD * HD) {
    int j = i - NFC;
    int k = j / HD, n = j - k * HD;
    w1T[n * HD + k] = f2bf(w1[j]);
  }
}

// ---------------- MFMA GEMM: featb = bf16(h @ fc_w[m])  ----------------------
__global__ __launch_bounds__(256)
void gemm_feat_mfma(const float* __restrict__ A,            // h [N,256] f32
                    const unsigned short* __restrict__ BT,  // fcwT [128][256] bf16
                    unsigned short* __restrict__ Cb,        // featb [N,128] bf16
                    int nrows) {
  __shared__ unsigned short As[64 * 40];
  __shared__ unsigned short Bs[128 * 40];
  int tid = threadIdx.x;
  int w = tid >> 6, l = tid & 63, q = l >> 4, s = l & 15;
  int row0 = blockIdx.x * 64;
  f32x4 acc[8] = {};
  for (int k0 = 0; k0 < IN_DIM; k0 += 32) {
    {
      int r = tid >> 2, c = (tid & 3) * 8;
      int gr = row0 + r;
      float4 a0, a1;
      if (gr < nrows) {
        a0 = *(const float4*)(A + (size_t)gr * IN_DIM + k0 + c);
        a1 = *(const float4*)(A + (size_t)gr * IN_DIM + k0 + c + 4);
      } else {
        a0 = make_float4(0.f, 0.f, 0.f, 0.f); a1 = a0;
      }
      ushort4 u0, u1;
      u0.x = f2bf(a0.x); u0.y = f2bf(a0.y); u0.z = f2bf(a0.z); u0.w = f2bf(a0.w);
      u1.x = f2bf(a1.x); u1.y = f2bf(a1.y); u1.z = f2bf(a1.z); u1.w = f2bf(a1.w);
      *(ushort4*)&As[r * 40 + c]     = u0;
      *(ushort4*)&As[r * 40 + c + 4] = u1;
    }
    {
      int n = tid >> 1, c = (tid & 1) * 16;
      uint4 b0 = *(const uint4*)(BT + (size_t)n * IN_DIM + k0 + c);
      uint4 b1 = *(const uint4*)(BT + (size_t)n * IN_DIM + k0 + c + 8);
      *(uint4*)&Bs[n * 40 + c]     = b0;
      *(uint4*)&Bs[n * 40 + c + 8] = b1;
    }
    __syncthreads();
    bf16x8 af = *(bf16x8*)&As[(w * 16 + s) * 40 + q * 8];
    #pragma unroll
    for (int f = 0; f < 8; ++f) {
      bf16x8 bf = *(bf16x8*)&Bs[(f * 16 + s) * 40 + q * 8];
      acc[f] = __builtin_amdgcn_mfma_f32_16x16x32_bf16(af, bf, acc[f], 0, 0, 0);
    }
    __syncthreads();
  }
  #pragma unroll
  for (int f = 0; f < 8; ++f) {
    #pragma unroll
    for (int r = 0; r < 4; ++r) {
      int gr = row0 + w * 16 + q * 4 + r;
      if (gr < nrows) Cb[(size_t)gr * HD + f * 16 + s] = f2bf(acc[f][r]);
    }
  }
}

// ---------------- el/er per (node, head), from bf16 feat ----------------------
__global__ __launch_bounds__(256)
void el_er_kernel(const unsigned short* __restrict__ feat,
                  const float* __restrict__ al, const float* __restrict__ ar,
                  float* __restrict__ el, float* __restrict__ er) {
  int i = blockIdx.x * blockDim.x + threadIdx.x;
  if (i >= N_NODES * HEADS) return;
  int node = i >> 3, hh = i & 7;
  const unsigned short* f = feat + (size_t)node * HD + hh * HID;
  float sl = 0.f, sr = 0.f;
  #pragma unroll
  for (int d = 0; d < HID; ++d) {
    float v = bf2f(f[d]);
    sl += v * al[hh * HID + d];
    sr += v * ar[hh * HID + d];
  }
  el[i] = sl; er[i] = sr;
}

// ---------------- batched CSR build ------------------------------------------
__global__ __launch_bounds__(256)
void hist_kernel(const int* __restrict__ edges, int* __restrict__ cnt) {
  int p = blockIdx.y;
  int e = blockIdx.x * 256 + threadIdx.x;
  if (e < N_EDGES)
    atomicAdd(&cnt[p * N_NODES + edges[(size_t)p * 2 * N_EDGES + N_EDGES + e]], 1);
}

__global__ __launch_bounds__(1024)
void scan1_kernel(const int* __restrict__ cnt, int* __restrict__ bsum, int n) {
  __shared__ int ws[16];
  int tid = threadIdx.x, lane = tid & 63, wid = tid >> 6;
  int i = blockIdx.x * 1024 + tid;
  int v = (i < n) ? cnt[i] : 0;
  #pragma unroll
  for (int d = 32; d; d >>= 1) v += __shfl_xor(v, d);
  if (lane == 0) ws[wid] = v;
  __syncthreads();
  if (tid == 0) {
    int s = 0;
    #pragma unroll
    for (int k = 0; k < 16; ++k) s += ws[k];
    bsum[blockIdx.x] = s;
  }
}

__global__ __launch_bounds__(64)
void scan2_kernel(const int* __restrict__ bsum, int* __restrict__ bbase,
                  int* __restrict__ offs_end, int nb) {
  int lane = threadIdx.x;
  int carry = 0;
  for (int base = 0; base < nb; base += 64) {
    int i = base + lane;
    int v = (i < nb) ? bsum[i] : 0;
    int s = v;
    #pragma unroll
    for (int d = 1; d < 64; d <<= 1) {
      int t = __shfl_up(s, d);
      if (lane >= d) s += t;
    }
    if (i < nb) bbase[i] = carry + s - v;
    carry += __shfl(s, 63);
  }
  if (lane == 0) *offs_end = carry;
}

__global__ __launch_bounds__(1024)
void scan3_kernel(const int* __restrict__ cnt, const int* __restrict__ bbase,
                  int* __restrict__ offs, int n) {
  __shared__ int wsum[16];
  int tid = threadIdx.x, lane = tid & 63, wid = tid >> 6;
  int i = blockIdx.x * 1024 + tid;
  int v = (i < n) ? cnt[i] : 0;
  int s = v;
  #pragma unroll
  for (int d = 1; d < 64; d <<= 1) {
    int t = __shfl_up(s, d);
    if (lane >= d) s += t;
  }
  if (lane == 63) wsum[wid] = s;
  __syncthreads();
  if (wid == 0 && lane < 16) {
    int x = wsum[lane];
    #pragma unroll
    for (int d = 1; d < 16; d <<= 1) {
      int t = __shfl_up(x, d);
      if (lane >= d) x += t;
    }
    wsum[lane] = x;
  }
  __syncthreads();
  int woff = (wid == 0) ? 0 : wsum[wid - 1];
  if (i < n) offs[i] = bbase[blockIdx.x] + woff + s - v;
}

__global__ __launch_bounds__(256)
void scatter_kernel(const int* __restrict__ edges, const int* __restrict__ offs,
                    int* __restrict__ fill, int* __restrict__ csr) {
  int p = blockIdx.y;
  int e = blockIdx.x * 256 + threadIdx.x;
  if (e >= N_EDGES) return;
  int s = edges[(size_t)p * 2 * N_EDGES + e];
  int d = edges[(size_t)p * 2 * N_EDGES + N_EDGES + e];
  int pos = offs[p * N_NODES + d] + atomicAdd(&fill[p * N_NODES + d], 1);
  csr[pos] = s;
}

// ---------------- GAT aggregation (no max pass, bf16 gather) ------------------
__global__ __launch_bounds__(256)
void aggregate_kernel(const int* __restrict__ offs, const int* __restrict__ csr,
                      const unsigned int* __restrict__ featb_u,  // [N][64] 2xbf16
                      const float* __restrict__ el, const float* __restrict__ er,
                      unsigned int* __restrict__ z_u) {           // [N][64] 2xbf16
  int node = blockIdx.x * 4 + (threadIdx.x >> 6);
  if (node >= N_NODES) return;
  int lane = threadIdx.x & 63;
  int hh = lane >> 3;
  int beg = offs[node], end = offs[node + 1];
  float erh = er[node * HEADS + hh];
  float ssum = 0.f, a0 = 0.f, a1 = 0.f;
  int i = beg;
  for (; i + 1 < end; i += 2) {
    int s0 = csr[i], s1 = csr[i + 1];
    float e0 = el[s0 * HEADS + hh] + erh;
    float e1 = el[s1 * HEADS + hh] + erh;
    unsigned int v0 = featb_u[(size_t)s0 * 64 + lane];
    unsigned int v1 = featb_u[(size_t)s1 * 64 + lane];
    e0 = e0 > 0.f ? e0 : 0.2f * e0;
    e1 = e1 > 0.f ? e1 : 0.2f * e1;
    float w0 = __expf(e0), w1 = __expf(e1);
    ssum += w0 + w1;
    a0 += w0 * __uint_as_float(v0 << 16) + w1 * __uint_as_float(v1 << 16);
    a1 += w0 * __uint_as_float(v0 & 0xffff0000u) + w1 * __uint_as_float(v1 & 0xffff0000u);
  }
  if (i < end) {
    int s0 = csr[i];
    float e0 = el[s0 * HEADS + hh] + erh;
    unsigned int v0 = featb_u[(size_t)s0 * 64 + lane];
    e0 = e0 > 0.f ? e0 : 0.2f * e0;
    float w0 = __expf(e0);
    ssum += w0;
    a0 += w0 * __uint_as_float(v0 << 16);
    a1 += w0 * __uint_as_float(v0 & 0xffff0000u);
  }
  float inv = (end > beg) ? 1.f / ssum : 0.f;
  a0 *= inv; a1 *= inv;
  a0 = a0 > 0.f ? a0 : expm1f(a0);
  a1 = a1 > 0.f ? a1 : expm1f(a1);
  unsigned int packed = (unsigned int)f2bf(a0) | ((unsigned int)f2bf(a1) << 16);
  z_u[(size_t)node * 64 + lane] = packed;
}

// ---------------- MFMA GEMM + tanh/w2 epilogue: wnode + max -------------------
__global__ __launch_bounds__(256)
void w_gemm_mfma(const unsigned short* __restrict__ Zb,    // [N,128] bf16
                 const unsigned short* __restrict__ BT,    // w1T [128][128] bf16
                 const float* __restrict__ B1, const float* __restrict__ W2,
                 float* __restrict__ wnode, unsigned int* __restrict__ wmax_enc,
                 int nrows) {
  __shared__ unsigned short As[64 * 40];
  __shared__ unsigned short Bs[128 * 40];
  __shared__ float redmax[4];
  int tid = threadIdx.x;
  int w = tid >> 6, l = tid & 63, q = l >> 4, s = l & 15;
  int row0 = blockIdx.x * 64;
  f32x4 acc[8] = {};
  for (int k0 = 0; k0 < HD; k0 += 32) {
    {
      int r = tid >> 2, c = (tid & 3) * 8;
      int gr = row0 + r;
      uint4 a0 = make_uint4(0, 0, 0, 0);
      if (gr < nrows) a0 = *(const uint4*)(Zb + (size_t)gr * HD + k0 + c);
      *(uint4*)&As[r * 40 + c] = a0;
    }
    {
      int n = tid >> 1, c = (tid & 1) * 16;
      uint4 b0 = *(const uint4*)(BT + (size_t)n * HD + k0 + c);
      uint4 b1 = *(const uint4*)(BT + (size_t)n * HD + k0 + c + 8);
      *(uint4*)&Bs[n * 40 + c]     = b0;
      *(uint4*)&Bs[n * 40 + c + 8] = b1;
    }
    __syncthreads();
    bf16x8 af = *(bf16x8*)&As[(w * 16 + s) * 40 + q * 8];
    #pragma unroll
    for (int f = 0; f < 8; ++f) {
      bf16x8 bf = *(bf16x8*)&Bs[(f * 16 + s) * 40 + q * 8];
      acc[f] = __builtin_amdgcn_mfma_f32_16x16x32_bf16(af, bf, acc[f], 0, 0, 0);
    }
    __syncthreads();
  }
  float b1v[8], w2v[8];
  #pragma unroll
  for (int f = 0; f < 8; ++f) { b1v[f] = B1[f * 16 + s]; w2v[f] = W2[f * 16 + s]; }
  float lmax = -1e30f;
  #pragma unroll
  for (int r = 0; r < 4; ++r) {
    float p = 0.f;
    #pragma unroll
    for (int f = 0; f < 8; ++f) p += tanhf(acc[f][r] + b1v[f]) * w2v[f];
    p += __shfl_xor(p, 1); p += __shfl_xor(p, 2);
    p += __shfl_xor(p, 4); p += __shfl_xor(p, 8);
    int gr = row0 + w * 16 + q * 4 + r;
    if (gr < nrows) {
      if (s == 0) wnode[gr] = p;
      lmax = fmaxf(lmax, p);
    }
  }
  #pragma unroll
  for (int d = 32; d; d >>= 1) lmax = fmaxf(lmax, __shfl_xor(lmax, d));
  if (l == 0) redmax[w] = lmax;
  __syncthreads();
  if (tid == 0) {
    float m = fmaxf(fmaxf(redmax[0], redmax[1]), fmaxf(redmax[2], redmax[3]));
    atomicMax(wmax_enc, encf(m));
  }
}

// ---------------- softmax-over-nodes fused accumulation ----------------------
__global__ __launch_bounds__(128)
void fused_acc_kernel(const unsigned short* __restrict__ zb,
                      const float* __restrict__ wnode,
                      const unsigned int* __restrict__ wmax_enc,
                      float* __restrict__ num, float* __restrict__ den, int n) {
  int t = threadIdx.x;
  float wm = decf(*wmax_enc);
  float ln = 0.f, ld = 0.f;
  for (int node = blockIdx.x; node < n; node += gridDim.x) {
    float e = __expf(wnode[node] - wm);
    ln += e * bf2f(zb[(size_t)node * HD + t]);
    ld += e;
  }
  atomicAdd(&num[t], ln);
  if (t == 0) atomicAdd(den, ld);
}

// ---------------- final ------------------------------------------------------
__global__ void final_kernel(const float* __restrict__ num, const float* __restrict__ den,
                             const float* __restrict__ PW, const float* __restrict__ PB,
                             float* __restrict__ out) {
  int t = threadIdx.x;
  if (t >= N_META * OUT_DIM) return;
  int m = t >> 3, o = t & 7;
  float inv = 1.0f / den[m];
  float s = 0.f;
  for (int k = 0; k < HD; ++k) s += num[m * HD + k] * PW[k * OUT_DIM + o];
  out[t] = s * inv + PB[o];
}

extern "C" void kernel_launch(void* const* d_in, const int* in_sizes, int n_in,
                              void* d_out, int out_size, void* d_ws, size_t ws_size,
                              hipStream_t stream) {
  (void)in_sizes; (void)n_in; (void)out_size; (void)ws_size;
  const float* h     = (const float*)d_in[0];
  const int*   edges = (const int*)d_in[1];
  const float* fcw   = (const float*)d_in[2];
  const float* al    = (const float*)d_in[3];
  const float* ar    = (const float*)d_in[4];
  const float* w1    = (const float*)d_in[5];
  const float* b1    = (const float*)d_in[6];
  const float* w2    = (const float*)d_in[7];
  const float* pw    = (const float*)d_in[8];
  const float* pb    = (const float*)d_in[9];
  float* out = (float*)d_out;

  char* ws = (char*)d_ws;
  size_t off = 0;
  auto alloc = [&](size_t bytes) -> void* {
    void* p = ws + off;
    off = (off + bytes + 255) & ~(size_t)255;
    return p;
  };
  unsigned short* featb = (unsigned short*)alloc((size_t)N_NODES * HD * 2);
  unsigned short* zb    = (unsigned short*)alloc((size_t)N_NODES * HD * 2);
  unsigned short* fcwT  = (unsigned short*)alloc((size_t)N_META * HD * IN_DIM * 2);
  unsigned short* w1T   = (unsigned short*)alloc((size_t)HD * HD * 2);
  float* el = (float*)alloc((size_t)N_NODES * HEADS * 4);
  float* er = (float*)alloc((size_t)N_NODES * HEADS * 4);
  int* cntfill = (int*)alloc((size_t)2 * N_META * N_NODES * 4);
  int* cnt  = cntfill;
  int* fill = cntfill + N_META * N_NODES;
  int* bsum  = (int*)alloc(256 * 4);
  int* bbase = (int*)alloc(256 * 4);
  int* offs  = (int*)alloc((size_t)(N_META * N_NODES + 1) * 4);
  int* csr   = (int*)alloc((size_t)N_META * N_EDGES * 4);
  float* wnode = (float*)alloc((size_t)N_NODES * 4);
  // numden block: num[3*128] | den[3] | wmax_enc[3]
  float* numden = (float*)alloc((N_META * HD + N_META + N_META) * 4);
  float* num = numden;
  float* den = numden + N_META * HD;
  unsigned int* wmax_enc = (unsigned int*)(numden + N_META * HD + N_META);

  hipMemsetAsync(numden, 0, (N_META * HD + N_META + N_META) * 4, stream);
  hipMemsetAsync(cntfill, 0, (size_t)2 * N_META * N_NODES * 4, stream);

  prep_kernel<<<(N_META * IN_DIM * HD + HD * HD + 255) / 256, 256, 0, stream>>>(
      fcw, w1, fcwT, w1T);

  const int NTOT = N_META * N_NODES;           // 150000
  const int NB = (NTOT + 1023) / 1024;         // 147
  dim3 egrid((N_EDGES + 255) / 256, N_META);
  hist_kernel<<<egrid, 256, 0, stream>>>(edges, cnt);
  scan1_kernel<<<NB, 1024, 0, stream>>>(cnt, bsum, NTOT);
  scan2_kernel<<<1, 64, 0, stream>>>(bsum, bbase, offs + NTOT, NB);
  scan3_kernel<<<NB, 1024, 0, stream>>>(cnt, bbase, offs, NTOT);
  scatter_kernel<<<egrid, 256, 0, stream>>>(edges, offs, fill, csr);

  dim3 ggrid((N_NODES + 63) / 64);
  for (int m = 0; m < N_META; ++m) {
    gemm_feat_mfma<<<ggrid, 256, 0, stream>>>(
        h, fcwT + (size_t)m * HD * IN_DIM, featb, N_NODES);
    el_er_kernel<<<(N_NODES * HEADS + 255) / 256, 256, 0, stream>>>(
        featb, al + m * HD, ar + m * HD, el, er);
    aggregate_kernel<<<(N_NODES + 3) / 4, 256, 0, stream>>>(
        offs + m * N_NODES, csr, (const unsigned int*)featb, el, er,
        (unsigned int*)zb);
    w_gemm_mfma<<<ggrid, 256, 0, stream>>>(
        zb, w1T, b1, w2, wnode, wmax_enc + m, N_NODES);
    fused_acc_kernel<<<256, 128, 0, stream>>>(
        zb, wnode, wmax_enc + m, num + m * HD, den + m, N_NODES);
  }
  final_kernel<<<1, 64, 0, stream>>>(num, den, pw, pb, out);
}